// Round 2
// baseline (538.500 us; speedup 1.0000x reference)
//
#include <hip/hip_runtime.h>

// EmbeddingBagCollection: T=8 tables, B=4096 bags, L=50 lookups, V=100000, D=128.
// out[b, t*D + d] = sum_l tables[t, indices[t,b,l], d]
//
// One 32-lane group per bag: lane owns float4 (32 x 16B = one 512B row).
// Block = 256 threads = 8 bags. Grid = 4096 blocks, t-major bag order so the
// resident window stays within ~1-2 tables (51.2MB each, fits 256MB L3 -> ~2x reuse).
//
// R5 (= R4 with compile fix): latency/MLP attack.
//  - Indices for the block's 8 bags (400 ints, contiguous) staged to LDS once
//    via a single coalesced int4 load.
//  - Fully-unrolled static software pipeline: 16-deep circular register
//    buffer buf[l % 16] with compile-time l (static VGPRs, no scratch).
//  - Nontemporal output stores via native ext_vector float4 (HIP float4 is a
//    class type the builtin rejects).

#define T_ 8
#define B_ 4096
#define L_ 50
#define V_ 100000
#define D_ 128
#define PF 16   // in-flight row loads per 32-lane group

typedef float nfloat4 __attribute__((ext_vector_type(4)));  // native vec for builtins

__global__ __launch_bounds__(256) void EmbeddingBagCollection_56959856279962_kernel(
    const int* __restrict__ indices,   // [T, B, L] int32
    const float* __restrict__ tables,  // [T, V, D] f32
    float* __restrict__ out)           // [B, T*D] f32
{
    __shared__ int sidx[8 * L_];                      // 400 ints = 1.6 KB

    const int tid  = threadIdx.x;
    const int bag0 = blockIdx.x << 3;                 // first bag of block

    // Stage this block's 400 indices (contiguous at indices + bag0*L_).
    // 400 ints = 100 int4; base offset bag0*L_*4 = blockIdx*1600 B, 16B-aligned.
    const int* __restrict__ ip = indices + bag0 * L_;
    if (tid < 100) {
        ((int4*)sidx)[tid] = ((const int4*)ip)[tid];
    }
    __syncthreads();

    const int group = tid >> 5;                       // bag within block
    const int lane  = tid & 31;                       // float4 within row
    const int t     = bag0 >> 12;                     // block-uniform table id
    const int b     = (bag0 + group) & (B_ - 1);

    const float* __restrict__ tbl = tables + (size_t)t * (V_ * D_); // scalar base
    const int*   __restrict__ gi  = sidx + group * L_;
    const unsigned laneoff = (unsigned)lane << 4;

    nfloat4 acc = (nfloat4)(0.f);
    nfloat4 buf[PF];

    // Prologue: fill the pipeline with PF independent row loads.
#pragma unroll
    for (int l = 0; l < PF; ++l) {
        const unsigned off = ((unsigned)gi[l] << 9) | laneoff;  // idx*512 + lane*16
        buf[l] = *(const nfloat4*)((const char*)tbl + off);
    }

    // Steady state: consume oldest, immediately refill its slot.
    // l is compile-time (full unroll) -> buf[l % PF] is a static VGPR tuple.
#pragma unroll
    for (int l = 0; l < L_; ++l) {
        const nfloat4 v = buf[l % PF];
        if (l + PF < L_) {
            const unsigned off = ((unsigned)gi[l + PF] << 9) | laneoff;
            buf[l % PF] = *(const nfloat4*)((const char*)tbl + off);
        }
        acc += v;
    }

    // out[b, t*D + lane*4 .. +3], one 512B row per group, nontemporal.
    nfloat4* __restrict__ op = (nfloat4*)(out + b * (T_ * D_) + t * D_) + lane;
    __builtin_nontemporal_store(acc, op);
}

extern "C" void kernel_launch(void* const* d_in, const int* in_sizes, int n_in,
                              void* d_out, int out_size, void* d_ws, size_t ws_size,
                              hipStream_t stream) {
    const int*   indices = (const int*)d_in[0];   // [T,B,L] int32
    const float* tables  = (const float*)d_in[1]; // [T,V,D] f32
    float*       out     = (float*)d_out;         // [B, T*D] f32

    const int grid = (T_ * B_) / 8;               // 4096 blocks, 8 bags each
    EmbeddingBagCollection_56959856279962_kernel<<<grid, 256, 0, stream>>>(
        indices, tables, out);
}

// Round 3
// 534.225 us; speedup vs baseline: 1.0080x; 1.0080x over previous
//
#include <hip/hip_runtime.h>

// EmbeddingBagCollection: T=8 tables, B=4096 bags, L=50 lookups, V=100000, D=128.
// out[b, t*D + d] = sum_l tables[t, indices[t,b,l], d]
//
// One 32-lane group per bag: lane owns float4 (32 x 16B = one 512B row).
// Block = 256 threads = 8 bags. Grid = 4096 blocks, t-major bag order.
//
// R6: locality attack. R5 (deep MLP) was exactly neutral -> not latency-bound;
// a shared resource saturates at ~1.56 TB/s for RANDOM 512B gathers (streaming
// fills hit 6.4 TB/s on this chip). Fix: per-group counting-sort of the 50
// indices into ascending 4096-row (2MB) buckets in LDS, then the identical
// 16-deep static-pipeline accumulate loop over the SORTED list. All resident
// blocks sweep buckets in the same order -> the whole GPU reads the table
// near-front-to-back: HBM first-touches become page-sequential, and the hot
// 2-8MB slice stays L2/L3-resident for the ~57% repeat accesses. Sum reorder
// only changes FP rounding order.

#define T_ 8
#define B_ 4096
#define L_ 50
#define V_ 100000
#define D_ 128
#define PF 16     // in-flight row loads per 32-lane group
#define BSH 12    // bucket = idx >> 12 (4096 rows = 2MB per bucket)
#define NB 26     // 100000 >> 12 = 24 max -> 25 buckets, pad to 26

typedef float nfloat4 __attribute__((ext_vector_type(4)));

__global__ __launch_bounds__(256) void EmbeddingBagCollection_56959856279962_kernel(
    const int* __restrict__ indices,   // [T, B, L] int32
    const float* __restrict__ tables,  // [T, V, D] f32
    float* __restrict__ out)           // [B, T*D] f32
{
    __shared__ int sidx[8 * L_];       // raw indices, 400 ints
    __shared__ int ssort[8 * L_];      // bucket-sorted indices
    __shared__ int scnt[8][NB];        // per-group bucket counts -> offsets

    const int tid  = threadIdx.x;
    const int bag0 = blockIdx.x << 3;  // first bag of block

    // Stage this block's 400 contiguous indices via one coalesced int4 load.
    const int* __restrict__ ip = indices + bag0 * L_;
    if (tid < 100) ((int4*)sidx)[tid] = ((const int4*)ip)[tid];
    if (tid < 8 * NB) ((int*)scnt)[tid] = 0;
    __syncthreads();

    const int group = tid >> 5;        // bag within block
    const int lane  = tid & 31;        // float4 within row

    // --- counting sort into ascending row-range buckets (per group) ---
    const int v0 = sidx[group * L_ + lane];
    atomicAdd(&scnt[group][v0 >> BSH], 1);
    int v1 = 0;
    if (lane < L_ - 32) {
        v1 = sidx[group * L_ + 32 + lane];
        atomicAdd(&scnt[group][v1 >> BSH], 1);
    }
    __syncthreads();

    if (lane == 0) {                   // serial exclusive prefix, 26 steps
        int run = 0;
#pragma unroll
        for (int bb = 0; bb < NB; ++bb) {
            const int c = scnt[group][bb];
            scnt[group][bb] = run;
            run += c;
        }
    }
    __syncthreads();

    {
        const int p = atomicAdd(&scnt[group][v0 >> BSH], 1);
        ssort[group * L_ + p] = v0;
        if (lane < L_ - 32) {
            const int p2 = atomicAdd(&scnt[group][v1 >> BSH], 1);
            ssort[group * L_ + p2] = v1;
        }
    }
    __syncthreads();

    // --- accumulate over sorted list, 16-deep static register pipeline ---
    const int t = bag0 >> 12;                          // block-uniform table id
    const int b = (bag0 + group) & (B_ - 1);
    const float* __restrict__ tbl = tables + (size_t)t * (V_ * D_);
    const int*   __restrict__ gi  = ssort + group * L_;
    const unsigned laneoff = (unsigned)lane << 4;

    nfloat4 acc = (nfloat4)(0.f);
    nfloat4 buf[PF];

#pragma unroll
    for (int l = 0; l < PF; ++l) {
        const unsigned off = ((unsigned)gi[l] << 9) | laneoff;  // idx*512+lane*16
        buf[l] = *(const nfloat4*)((const char*)tbl + off);
    }

#pragma unroll
    for (int l = 0; l < L_; ++l) {
        const nfloat4 v = buf[l % PF];                 // compile-time index
        if (l + PF < L_) {
            const unsigned off = ((unsigned)gi[l + PF] << 9) | laneoff;
            buf[l % PF] = *(const nfloat4*)((const char*)tbl + off);
        }
        acc += v;
    }

    // out[b, t*D + lane*4 .. +3], one 512B row per group, nontemporal.
    nfloat4* __restrict__ op = (nfloat4*)(out + b * (T_ * D_) + t * D_) + lane;
    __builtin_nontemporal_store(acc, op);
}

extern "C" void kernel_launch(void* const* d_in, const int* in_sizes, int n_in,
                              void* d_out, int out_size, void* d_ws, size_t ws_size,
                              hipStream_t stream) {
    const int*   indices = (const int*)d_in[0];   // [T,B,L] int32
    const float* tables  = (const float*)d_in[1]; // [T,V,D] f32
    float*       out     = (float*)d_out;         // [B, T*D] f32

    const int grid = (T_ * B_) / 8;               // 4096 blocks, 8 bags each
    EmbeddingBagCollection_56959856279962_kernel<<<grid, 256, 0, stream>>>(
        indices, tables, out);
}